// Round 2
// baseline (404.658 us; speedup 1.0000x reference)
//
#include <hip/hip_runtime.h>
#include <hip/hip_bf16.h>

// Downsample: 3x3 conv (96->48, s1, p1, no bias) + PixelUnshuffle(2), fused.
// x: (8,96,256,256) fp32; W: (48,96,3,3) fp32; out: (8,192,128,128) fp32.
//
// R5 = R4 with the __builtin_bit_cast compile error fixed (memcpy extract).
// R4 vs R3 (145us dispatch, latency-bound: MfmaUtil 11.7, HBM 33%, both idle
// in alternation):
//  - T14 async-STAGE split: chunk cc+1's 48 global loads issue into regs
//    BEFORE chunk cc's MFMA loop; pack(v_cvt_pk_bf16_f32)+ds_write after the
//    read-barrier. HBM stays busy under compute; latency off critical path.
//  - A-frag prefetch carried across chunk boundary (d==8 -> next cc, d=0):
//    no L2-latency stall at chunk start.
//  - pack via __float22bfloat162_rn (1 cvt_pk vs ~9 ALU per pair, same RNE).
//  - nontemporal C-stores (output is write-once, keep L2 for x halos).
//  - __launch_bounds__(256,3): cap combined VGPR ~170 (acc48+inflight48+frags).

typedef __attribute__((ext_vector_type(8))) short bf16x8;   // 8 bf16 (4 VGPRs)
typedef __attribute__((ext_vector_type(4))) float f32x4;    // MFMA C/D
typedef __attribute__((ext_vector_type(4))) unsigned uint4v;

#define CIN 96
#define COUT 48
#define HW 256
#define TH 8
#define TW 32
#define HALO_H (TH + 2)        // 10
#define HALO_W (TW + 2)        // 34
#define NPIX (HALO_H * HALO_W) // 340
#define CC 32                  // ci per chunk = one MFMA k-step
#define CIPAD 40               // padded ci stride (halfs): 80B = odd*16B
#define TASKS (4 * NPIX)       // 1360 staging tasks per chunk
#define NT 6                   // ceil(TASKS/256) tasks per thread

static __device__ __forceinline__ unsigned bfbits(float f) {
    unsigned u = __builtin_bit_cast(unsigned, f);
    return (u + 0x7fffu + ((u >> 16) & 1u)) >> 16;   // RNE
}
static __device__ __forceinline__ unsigned packbf(float lo, float hi) {
    // compiler emits v_cvt_pk_bf16_f32 (RNE, bit-identical to bfbits pair)
    __hip_bfloat162 h = __float22bfloat162_rn(float2{lo, hi});
    unsigned r;
    __builtin_memcpy(&r, &h, sizeof(r));
    return r;
}

// ---- kernel 1: W (48,96,3,3) fp32 -> MFMA A-frag blob bf16 in d_ws ----
// blob[cc][d][ct][lane][j], cc=ci>>5, d=3x3 tap, ct=co>>4,
// lane=(co&15)|((cl>>3)<<4), j=cl&7   (cl = ci&31). 3*9*3*64*8 halfs = 82944 B
__global__ __launch_bounds__(256) void wtransform(
    const float* __restrict__ Wg, short* __restrict__ blob)
{
    int t = blockIdx.x * 256 + threadIdx.x;          // = (co*96+ci)*9+d
    if (t >= COUT * CIN * 9) return;
    int co  = t / (CIN * 9);
    int rem = t - co * (CIN * 9);
    int ci  = rem / 9;
    int d   = rem - ci * 9;
    int cc  = ci >> 5, cl = ci & 31;
    int ct  = co >> 4;
    int lane = (co & 15) | ((cl >> 3) << 4);
    int j   = cl & 7;
    blob[((((cc * 9 + d) * 3 + ct) * 64 + lane) * 8) + j] = (short)bfbits(Wg[t]);
}

// ---- kernel 2: conv + unshuffle, software-pipelined staging ----
__global__ __launch_bounds__(256, 3) void conv3x3_unshuffle_mfma(
    const float* __restrict__ x,
    const short* __restrict__ wblob,
    float* __restrict__ out)
{
    __shared__ short xs[NPIX * CIPAD];               // 13600 halfs = 27200 B

    const int tid  = threadIdx.x;
    const int lane = tid & 63;
    const int wv   = tid >> 6;          // wave 0..3
    const int b    = blockIdx.z;
    const int h0   = blockIdx.y * TH;
    const int w0   = blockIdx.x * TW;

    const float* xb = x + (size_t)b * CIN * HW * HW;

    // per-thread LDS dests (chunk-invariant); -1 marks no-task
    int loff[NT];
#pragma unroll
    for (int k = 0; k < NT; ++k) {
        int t = tid + k * 256;
        if (t < TASKS) {
            int cig = t / NPIX;
            int p   = t - cig * NPIX;
            loff[k] = p * CIPAD + cig * 8;           // byte addr 80p+16cig: 16B aligned
        } else loff[k] = -1;
    }

    float vbuf[NT][8];                               // in-flight staging data

    // issue chunk cc's global loads into vbuf (no waits here)
    auto stage_issue = [&](int cc) {
#pragma unroll
        for (int k = 0; k < NT; ++k) {
            int t   = tid + k * 256;
            int cig = t / NPIX;                      // 0..3 (ci group of 8)
            int p   = t - cig * NPIX;                // 0..339
            int r   = p / HALO_W;
            int c   = p - r * HALO_W;
            int gh  = h0 + r - 1;
            int gw  = w0 + c - 1;
            bool inb = (t < TASKS) & ((unsigned)gh < HW) & ((unsigned)gw < HW);
            if (inb) {
                const float* src = xb + (size_t)(cc * CC + cig * 8) * HW * HW + gh * HW + gw;
#pragma unroll
                for (int j = 0; j < 8; ++j) vbuf[k][j] = src[(size_t)j * HW * HW];
            } else {
#pragma unroll
                for (int j = 0; j < 8; ++j) vbuf[k][j] = 0.f;
            }
        }
    };
    // pack + write LDS (compiler inserts the vmcnt waits on vbuf here)
    auto stage_commit = [&]() {
#pragma unroll
        for (int k = 0; k < NT; ++k) {
            if (loff[k] >= 0) {
                uint4v pk;
                pk.x = packbf(vbuf[k][0], vbuf[k][1]);
                pk.y = packbf(vbuf[k][2], vbuf[k][3]);
                pk.z = packbf(vbuf[k][4], vbuf[k][5]);
                pk.w = packbf(vbuf[k][6], vbuf[k][7]);
                *(uint4v*)&xs[loff[k]] = pk;
            }
        }
    };

    f32x4 acc[4][3];
#pragma unroll
    for (int pt = 0; pt < 4; ++pt)
#pragma unroll
        for (int ct = 0; ct < 3; ++ct)
            acc[pt][ct] = (f32x4){0.f, 0.f, 0.f, 0.f};

    // prologue: stage chunk 0 (only exposed latency of the kernel)
    stage_issue(0);
    stage_commit();

    // initial A-frag prefetch (cc=0, d=0) — overlaps the barrier
    bf16x8 afc[3];
#pragma unroll
    for (int ct = 0; ct < 3; ++ct)
        afc[ct] = *(const bf16x8*)(wblob + ct * 512 + lane * 8);

    __syncthreads();

    for (int cc = 0; cc < CIN / CC; ++cc) {
        // ---- issue NEXT chunk's loads before compute (hidden under MFMA) ----
        if (cc < 2) stage_issue(cc + 1);

        const short* wc = wblob + (size_t)cc * 9 * 3 * 512;  // 512 halfs per frag

#pragma unroll
        for (int d = 0; d < 9; ++d) {
            // A-frag prefetch, depth 1, carried across the chunk boundary
            const short* wn = (d < 8) ? (wc + (d + 1) * 3 * 512)
                                      : (cc < 2 ? wc + 9 * 3 * 512 : wc);
            bf16x8 afn[3];
#pragma unroll
            for (int ct = 0; ct < 3; ++ct)
                afn[ct] = *(const bf16x8*)(wn + ct * 512 + lane * 8);

            const int dy = d / 3, dx = d - 3 * (d / 3);
            bf16x8 bfv[4];
#pragma unroll
            for (int pt = 0; pt < 4; ++pt) {
                int hr = 2 * wv + (pt >> 1) + dy;
                int hc = (pt & 1) * 16 + (lane & 15) + dx;
                bfv[pt] = *(const bf16x8*)&xs[(hr * HALO_W + hc) * CIPAD + (lane >> 4) * 8];
            }
#pragma unroll
            for (int pt = 0; pt < 4; ++pt)
#pragma unroll
                for (int ct = 0; ct < 3; ++ct)
                    acc[pt][ct] = __builtin_amdgcn_mfma_f32_16x16x32_bf16(
                        afc[ct], bfv[pt], acc[pt][ct], 0, 0, 0);
#pragma unroll
            for (int ct = 0; ct < 3; ++ct) afc[ct] = afn[ct];
        }

        __syncthreads();                 // all waves done READING xs(cc)
        if (cc < 2) {
            stage_commit();              // loads long-landed; pack + ds_write
            __syncthreads();             // xs(cc+1) ready
        }
    }

    // ---- epilogue: PixelUnshuffle folded into addressing ----
    // C/D layout: col(pix) = lane&15, row(co) = (lane>>4)*4 + reg
#pragma unroll
    for (int pt = 0; pt < 4; ++pt) {
        int oh = h0 + 2 * wv + (pt >> 1);
        int ow = w0 + (pt & 1) * 16 + (lane & 15);
        int sub = ((oh & 1) << 1) | (ow & 1);
        size_t pixoff = (size_t)(oh >> 1) * (HW / 2) + (ow >> 1);
#pragma unroll
        for (int ct = 0; ct < 3; ++ct) {
#pragma unroll
            for (int e = 0; e < 4; ++e) {
                int co = ct * 16 + (lane >> 4) * 4 + e;
                __builtin_nontemporal_store(acc[pt][ct][e],
                    &out[((size_t)b * (COUT * 4) + co * 4 + sub) * (HW / 2) * (HW / 2) + pixoff]);
            }
        }
    }
}

extern "C" void kernel_launch(void* const* d_in, const int* in_sizes, int n_in,
                              void* d_out, int out_size, void* d_ws, size_t ws_size,
                              hipStream_t stream) {
    const float* x  = (const float*)d_in[0];   // 8*96*256*256
    const float* Wg = (const float*)d_in[1];   // 48*96*3*3
    float* out      = (float*)d_out;           // 8*192*128*128
    short* blob     = (short*)d_ws;            // 82944 B frag blob

    wtransform<<<(COUT * CIN * 9 + 255) / 256, 256, 0, stream>>>(Wg, blob);

    dim3 grid(HW / TW, HW / TH, 8);            // (8, 32, 8) = 2048 blocks
    conv3x3_unshuffle_mfma<<<grid, dim3(256), 0, stream>>>(x, blob, out);
}

// Round 3
// 388.561 us; speedup vs baseline: 1.0414x; 1.0414x over previous
//
#include <hip/hip_runtime.h>
#include <hip/hip_bf16.h>

// Downsample: 3x3 conv (96->48, s1, p1, no bias) + PixelUnshuffle(2), fused.
// x: (8,96,256,256) fp32; W: (48,96,3,3) fp32; out: (8,192,128,128) fp32.
//
// R6 vs R3 (145us): kill the barrier convoy.
//  - Each WAVE owns a private 4x16 output tile + private LDS region
//    (halo 6x18 = 108 pix x 80B = 8.64KB/wave; 34.56KB/block -> 4 blocks/CU).
//    NO __syncthreads anywhere: waves stream stage->compute independently;
//    within-wave LDS ordering is program-order (in-order LDS pipe).
//    -> resident waves keep loads in flight continuously (~28KB/CU vs ~16KB
//    with barriers) -> HBM toward saturation.
//  - Batch-per-XCD block swizzle: 2048 blocks, XCD k <- batch k, tiles
//    row-major within -> halo overlap between neighbor tiles is an L2 hit
//    (reuse distance ~660KB < 4MB/XCD).
//  - Normal stores (R5's nontemporal: +94MB HBM RMW traffic -> reverted).
//  - Register structure = R3's (no persistent vbuf): VGPR ~64-75, lb(256,4).

typedef __attribute__((ext_vector_type(8))) short bf16x8;   // 8 bf16 (4 VGPRs)
typedef __attribute__((ext_vector_type(4))) float f32x4;    // MFMA C/D
typedef __attribute__((ext_vector_type(4))) unsigned uint4v;

#define CIN 96
#define COUT 48
#define HW 256
// per-wave tile
#define WTH 4                  // output rows per wave
#define WTW 16                 // output cols per wave
#define WHH (WTH + 2)          // 6 halo rows
#define WHW (WTW + 2)          // 18 halo cols
#define WNP (WHH * WHW)        // 108 halo pixels
#define CC 32                  // ci per chunk = one MFMA k-step
#define CIPAD 40               // padded ci stride (halfs): 80B = odd*16B

static __device__ __forceinline__ unsigned bfbits(float f) {
    unsigned u = __builtin_bit_cast(unsigned, f);
    return (u + 0x7fffu + ((u >> 16) & 1u)) >> 16;   // RNE
}
static __device__ __forceinline__ unsigned packbf(float lo, float hi) {
    // emits v_cvt_pk_bf16_f32 (RNE, bit-identical to bfbits pair)
    __hip_bfloat162 h = __float22bfloat162_rn(float2{lo, hi});
    unsigned r;
    __builtin_memcpy(&r, &h, sizeof(r));
    return r;
}

// ---- kernel 1: W (48,96,3,3) fp32 -> MFMA A-frag blob bf16 in d_ws ----
// blob[cc][d][ct][lane][j], cc=ci>>5, d=3x3 tap, ct=co>>4,
// lane=(co&15)|((cl>>3)<<4), j=cl&7   (cl = ci&31). 3*9*3*64*8 halfs = 82944 B
__global__ __launch_bounds__(256) void wtransform(
    const float* __restrict__ Wg, short* __restrict__ blob)
{
    int t = blockIdx.x * 256 + threadIdx.x;          // = (co*96+ci)*9+d
    if (t >= COUT * CIN * 9) return;
    int co  = t / (CIN * 9);
    int rem = t - co * (CIN * 9);
    int ci  = rem / 9;
    int d   = rem - ci * 9;
    int cc  = ci >> 5, cl = ci & 31;
    int ct  = co >> 4;
    int lane = (co & 15) | ((cl >> 3) << 4);
    int j   = cl & 7;
    blob[((((cc * 9 + d) * 3 + ct) * 64 + lane) * 8) + j] = (short)bfbits(Wg[t]);
}

// ---- kernel 2: conv + unshuffle, barrier-free wave-private tiles ----
__global__ __launch_bounds__(256, 4) void conv3x3_unshuffle_mfma(
    const float* __restrict__ x,
    const short* __restrict__ wblob,
    float* __restrict__ out)
{
    __shared__ short xs[4][WNP * CIPAD];             // 4 x 8640 B = 34560 B

    const int tid  = threadIdx.x;
    const int lane = tid & 63;
    const int wv   = tid >> 6;                       // wave 0..3

    // batch-per-XCD swizzle: bid&7 = XCD -> batch; tiles row-major within.
    // 2048 blocks = 8 batches x (16x16) tiles; bijective (2048 % 8 == 0).
    int bid = blockIdx.x;
    int nid = (bid & 7) * 256 + (bid >> 3);
    int b   = nid >> 8;                              // batch 0..7
    int ty  = (nid >> 4) & 15;
    int tx  = nid & 15;
    int h0  = ty * 16 + wv * WTH;                    // this wave's first out row
    int w0  = tx * 16;

    const float* xb = x + (size_t)b * CIN * HW * HW;
    short* xw = xs[wv];                              // wave-private LDS region

    f32x4 acc[WTH][3];
#pragma unroll
    for (int pt = 0; pt < WTH; ++pt)
#pragma unroll
        for (int ct = 0; ct < 3; ++ct)
            acc[pt][ct] = (f32x4){0.f, 0.f, 0.f, 0.f};

    // A-frag prefetch (cc=0, d=0)
    bf16x8 afc[3];
#pragma unroll
    for (int ct = 0; ct < 3; ++ct)
        afc[ct] = *(const bf16x8*)(wblob + ct * 512 + lane * 8);

    for (int cc = 0; cc < CIN / CC; ++cc) {
        // ---- stage this wave's halo chunk: 108 pix x 32 ci -> bf16 LDS ----
        // task = (cig 0..3, p = lane or lane+64); 8 dword loads + 4 cvt_pk
        // + 1 ds_write_b128. Coalesced: 16-lane runs hit contiguous gw.
#pragma unroll
        for (int cig = 0; cig < 4; ++cig) {
#pragma unroll
            for (int rep = 0; rep < 2; ++rep) {
                int p = lane + rep * 64;
                bool act = p < WNP;                  // rep=1: 44/64 lanes
                int r = p / WHW;
                int c = p - r * WHW;
                int gh = h0 + r - 1;
                int gw = w0 + c - 1;
                float v[8];
#pragma unroll
                for (int j = 0; j < 8; ++j) v[j] = 0.f;
                if (act & ((unsigned)gh < HW) & ((unsigned)gw < HW)) {
                    const float* src = xb + (size_t)(cc * CC + cig * 8) * HW * HW
                                          + gh * HW + gw;
#pragma unroll
                    for (int j = 0; j < 8; ++j) v[j] = src[(size_t)j * HW * HW];
                }
                if (act) {
                    uint4v pk;
                    pk.x = packbf(v[0], v[1]);
                    pk.y = packbf(v[2], v[3]);
                    pk.z = packbf(v[4], v[5]);
                    pk.w = packbf(v[6], v[7]);
                    *(uint4v*)&xw[p * CIPAD + cig * 8] = pk;  // 80p+16cig: 16B-aligned
                }
            }
        }
        // no barrier: LDS ops are in-order within the wave; compiler orders
        // the ds_reads below behind these ds_writes via lgkmcnt.

        // ---- 9 shifted GEMM k-steps; A-frags from global blob, depth-1 ----
        const short* wc = wblob + (size_t)cc * 9 * 3 * 512;   // 512 halfs/frag
#pragma unroll
        for (int d = 0; d < 9; ++d) {
            const short* wn = (d < 8) ? (wc + (d + 1) * 3 * 512)
                                      : (cc < 2 ? wc + 9 * 3 * 512 : wc);
            bf16x8 afn[3];
#pragma unroll
            for (int ct = 0; ct < 3; ++ct)
                afn[ct] = *(const bf16x8*)(wn + ct * 512 + lane * 8);

            const int dy = d / 3, dx = d - 3 * (d / 3);
            bf16x8 bfv[WTH];
#pragma unroll
            for (int pt = 0; pt < WTH; ++pt) {
                int hr = pt + dy;                    // 0..5
                int hc = (lane & 15) + dx;           // 0..17
                bfv[pt] = *(const bf16x8*)&xw[(hr * WHW + hc) * CIPAD + (lane >> 4) * 8];
            }
#pragma unroll
            for (int pt = 0; pt < WTH; ++pt)
#pragma unroll
                for (int ct = 0; ct < 3; ++ct)
                    acc[pt][ct] = __builtin_amdgcn_mfma_f32_16x16x32_bf16(
                        afc[ct], bfv[pt], acc[pt][ct], 0, 0, 0);
#pragma unroll
            for (int ct = 0; ct < 3; ++ct) afc[ct] = afn[ct];
        }
    }

    // ---- epilogue: PixelUnshuffle folded into addressing (normal stores) ----
    // C/D layout: col(pix) = lane&15, row(co) = (lane>>4)*4 + reg
#pragma unroll
    for (int pt = 0; pt < WTH; ++pt) {
        int oh = h0 + pt;
        int ow = w0 + (lane & 15);
        int sub = ((oh & 1) << 1) | (ow & 1);
        size_t pixoff = (size_t)(oh >> 1) * (HW / 2) + (ow >> 1);
#pragma unroll
        for (int ct = 0; ct < 3; ++ct) {
#pragma unroll
            for (int e = 0; e < 4; ++e) {
                int co = ct * 16 + (lane >> 4) * 4 + e;
                out[((size_t)b * (COUT * 4) + co * 4 + sub) * (HW / 2) * (HW / 2) + pixoff] =
                    acc[pt][ct][e];
            }
        }
    }
}

extern "C" void kernel_launch(void* const* d_in, const int* in_sizes, int n_in,
                              void* d_out, int out_size, void* d_ws, size_t ws_size,
                              hipStream_t stream) {
    const float* x  = (const float*)d_in[0];   // 8*96*256*256
    const float* Wg = (const float*)d_in[1];   // 48*96*3*3
    float* out      = (float*)d_out;           // 8*192*128*128
    short* blob     = (short*)d_ws;            // 82944 B frag blob

    wtransform<<<(COUT * CIN * 9 + 255) / 256, 256, 0, stream>>>(Wg, blob);

    conv3x3_unshuffle_mfma<<<dim3(2048), dim3(256), 0, stream>>>(x, blob, out);
}